// Round 18
// baseline (1143.795 us; speedup 1.0000x reference)
//
#include <hip/hip_runtime.h>
#include <stdint.h>

#define L_ 12
#define B_ 8
#define T_ 512
#define D_ 768
#define H_ 12
#define DH_ 64
#define M_ 4096               // B_*T_ rows
#define DD_ (D_*D_)

typedef unsigned short u16;
typedef __bf16 bf16x8 __attribute__((ext_vector_type(8)));
typedef float f32x4 __attribute__((ext_vector_type(4)));
typedef u16 u16x4 __attribute__((ext_vector_type(4)));

#define WAIT_VM(N) asm volatile("s_waitcnt vmcnt(" #N ")" ::: "memory")

static __device__ __forceinline__ u16 f2b(float f) {
  union { float f; unsigned u; } x; x.f = f;
  unsigned r = x.u + 0x7fffu + ((x.u >> 16) & 1u);   // RNE
  return (u16)(r >> 16);
}
static __device__ __forceinline__ float b2f(u16 u) {
  union { unsigned u; float f; } x; x.u = ((unsigned)u) << 16; return x.f;
}
static __device__ __forceinline__ void gload16(u16* lds, const u16* g) {
  __builtin_amdgcn_global_load_lds((__attribute__((address_space(1))) void*)(g),
                                   (__attribute__((address_space(3))) void*)(lds), 16, 0, 0);
}
static __device__ __forceinline__ f32x4 mfma16(bf16x8 a, bf16x8 b, f32x4 c) {
  return __builtin_amdgcn_mfma_f32_16x16x32_bf16(a, b, c, 0, 0, 0);
}
static __device__ __forceinline__ bf16x8 ldfrag(const u16* p) {
  return *reinterpret_cast<const bf16x8*>(p);
}

// ---------------- init: f32 -> bf16 copies ----------------
__global__ void init_kernel(const float* __restrict__ qs, const float* __restrict__ hs,
                            u16* __restrict__ qsb, u16* __restrict__ hidb, int n) {
  int i = blockIdx.x * 256 + threadIdx.x;
  if (i < n) {
    qsb[i] = f2b(qs[i]);
    hidb[i] = f2b(hs[i]);
  }
}

// ---------------- weight transpose+convert v3: W[k][n] f32 -> Wt[n][k] bf16 ----------------
__global__ void wt_kernel(const float* W0, const float* W1, const float* W2,
                          const float* W3, const float* W4, u16* __restrict__ out) {
  const int z = blockIdx.y, layer = z / 5, w = z % 5;
  const float* base = (w == 0) ? W0 : (w == 1) ? W1 : (w == 2) ? W2 : (w == 3) ? W3 : W4;
  const float* W = base + (size_t)layer * DD_;
  u16* O = out + (size_t)z * DD_;
  const int nb = blockIdx.x * 32;
  __shared__ u16 tile[32][772];             // stride 1544B: 8B-aligned rows
  const int t = threadIdx.x;
  #pragma unroll
  for (int p = 0; p < 6; ++p) {
    const int g = p * 256 + t;              // 0..1535 : 16-elem groups (4k x 4n)
    const int n4 = (g & 7) * 4, kr4 = (g >> 3) * 4;
    f32x4 v[4];
    #pragma unroll
    for (int j = 0; j < 4; j++)
      v[j] = *reinterpret_cast<const f32x4*>(W + (size_t)(kr4 + j) * D_ + nb + n4);
    #pragma unroll
    for (int i = 0; i < 4; i++) {
      u16x4 w4;
      #pragma unroll
      for (int j = 0; j < 4; j++) w4[j] = f2b(v[j][i]);
      *reinterpret_cast<u16x4*>(&tile[n4 + i][kr4]) = w4;
    }
  }
  __syncthreads();
  #pragma unroll
  for (int p = 0; p < 24; ++p) {
    const int q = p * 256 + t;              // 0..6143 quads
    const int n = q / 192, k4 = (q - n * 192) * 4;
    const u16x4 o4 = *reinterpret_cast<const u16x4*>(&tile[n][k4]);
    *reinterpret_cast<u16x4*>(O + (size_t)(nb + n) * D_ + k4) = o4;
  }
}

// ---------------- GEMM core 64x128, BK=64, 3-buffer 2-deep counted-vmcnt pipeline ----------------
// Per-wave 6 VMEM/tile. Prologue stages tiles 0,1. Steady state: WAIT_VM(6) (tile kt landed,
// kt+1 in flight) -> s_barrier -> stage kt+2 -> ds_read+MFMA -> s_barrier. WAR: buffer rewritten
// one full iteration after its last read (3-buffer rotation). qall/gemm128 untouched (control).
static __device__ void gemm_core(const u16* __restrict__ A, const u16* __restrict__ W,
                                 const float* __restrict__ bias, const u16* __restrict__ resb,
                                 float* __restrict__ outf, u16* __restrict__ outb,
                                 u16* __restrict__ outv) {
  __shared__ __align__(16) u16 lA[3][64 * 64];    // 24KB
  __shared__ __align__(16) u16 lB[3][128 * 64];   // 48KB
  const int tid = threadIdx.x;
  const int wave = tid >> 6, lane = tid & 63;
  const int wm = wave >> 1, wn = wave & 1;

  const int nbx = gridDim.x;                      // 6
  const int nwg = nbx * gridDim.y;                // 384 per z-plane
  const int orig = blockIdx.y * nbx + blockIdx.x;
  const int cpx = nwg >> 3;
  const int swz = (orig & 7) * cpx + (orig >> 3);
  const int m0 = (swz / nbx) * 64, n0 = (swz % nbx) * 128;
  const int lr = lane & 15, lg = lane >> 4;

  f32x4 acc[2][4];
  #pragma unroll
  for (int i = 0; i < 2; i++)
    #pragma unroll
    for (int j = 0; j < 4; j++) acc[i][j] = f32x4{0.f, 0.f, 0.f, 0.f};

  const int uA0 = wave * 64 + lane, uA1 = 256 + uA0;
  const int rA0 = uA0 >> 3, cA0 = ((uA0 & 7) ^ (rA0 & 7)) << 3;
  const int rA1 = uA1 >> 3, cA1 = ((uA1 & 7) ^ (rA1 & 7)) << 3;
  const u16* Ab0 = A + (size_t)(m0 + rA0) * D_ + cA0;
  const u16* Ab1 = A + (size_t)(m0 + rA1) * D_ + cA1;
  const u16* Wb[4];
  #pragma unroll
  for (int q = 0; q < 4; ++q) {
    const int u = q * 256 + wave * 64 + lane;
    const int r = u >> 3, c = ((u & 7) ^ (r & 7)) << 3;
    Wb[q] = W + (size_t)(n0 + r) * D_ + c;
  }

#define STAGE(buf, k0_) do {                                   \
    gload16(lA[buf] + wave * 512,        Ab0 + (k0_));         \
    gload16(lA[buf] + 2048 + wave * 512, Ab1 + (k0_));         \
    gload16(lB[buf] + wave * 512,        Wb[0] + (k0_));       \
    gload16(lB[buf] + 2048 + wave * 512, Wb[1] + (k0_));       \
    gload16(lB[buf] + 4096 + wave * 512, Wb[2] + (k0_));       \
    gload16(lB[buf] + 6144 + wave * 512, Wb[3] + (k0_));       \
  } while (0)

  STAGE(0, 0);
  STAGE(1, 64);

  const int sx = lr & 7;

  int cur = 0;
  for (int kt = 0; kt < 12; ++kt) {
    if (kt < 11) { WAIT_VM(6); } else { WAIT_VM(0); }
    __builtin_amdgcn_s_barrier();            // all waves' tile-kt loads landed
    if (kt < 10) {
      int s = cur + 2; if (s >= 3) s -= 3;
      STAGE(s, (kt + 2) * 64);               // 2 tiles in flight across barriers
    }
    bf16x8 af[2][2], bw[2][4];
    #pragma unroll
    for (int kk = 0; kk < 2; ++kk) {
      const int uo = ((kk * 4 + lg) ^ sx) << 3;
      #pragma unroll
      for (int i = 0; i < 2; i++)
        af[kk][i] = ldfrag(lA[cur] + ((wm * 32 + i * 16 + lr) << 6) + uo);
      #pragma unroll
      for (int j = 0; j < 4; j++)
        bw[kk][j] = ldfrag(lB[cur] + ((wn * 64 + j * 16 + lr) << 6) + uo);
    }
    #pragma unroll
    for (int kk = 0; kk < 2; ++kk)
      #pragma unroll
      for (int i = 0; i < 2; i++)
        #pragma unroll
        for (int j = 0; j < 4; j++)
          acc[i][j] = mfma16(af[kk][i], bw[kk][j], acc[i][j]);
    __builtin_amdgcn_s_barrier();            // readers of buf cur done before its rewrite
    cur = (cur == 2) ? 0 : cur + 1;
  }
#undef STAGE

  if (outv) {
    #pragma unroll
    for (int j = 0; j < 4; j++) {
      const int colg = n0 + wn * 64 + j * 16 + lr;
      const float bv = bias[colg];
      const int h = colg >> 6, dh = colg & 63;
      #pragma unroll
      for (int i = 0; i < 2; i++) {
        const int rowb = m0 + wm * 32 + i * 16 + lg * 4;
        const int bb = rowb >> 9, tt = rowb & 511;
        u16x4 o4;
        #pragma unroll
        for (int r = 0; r < 4; r++) o4[r] = f2b(acc[i][j][r] + bv);
        *reinterpret_cast<u16x4*>(outv + ((size_t)((bb * H_ + h) * DH_ + dh)) * T_ + tt) = o4;
      }
    }
    return;
  }
  #pragma unroll
  for (int j = 0; j < 4; j++) {
    const int colg = n0 + wn * 64 + j * 16 + lr;
    const float bv = bias[colg];
    #pragma unroll
    for (int i = 0; i < 2; i++) {
      const int rowb = m0 + wm * 32 + i * 16 + lg * 4;
      #pragma unroll
      for (int r = 0; r < 4; r++) {
        float v = acc[i][j][r] + bv;
        const size_t off = (size_t)(rowb + r) * D_ + colg;
        if (resb) v += b2f(resb[off]);
        if (outf) outf[off] = v;
        if (outb) outb[off] = f2b(v);
      }
    }
  }
}

// ---------------- GEMM core 128x128, BK=64 (qall only; unchanged control) ----------------
static __device__ void gemm128_core(const u16* __restrict__ A, const u16* __restrict__ W,
                                    const float* __restrict__ bias, u16* __restrict__ outb) {
  __shared__ __align__(16) u16 lA[2][128 * 64];
  __shared__ __align__(16) u16 lB[2][128 * 64];
  const int tid = threadIdx.x;
  const int wave = tid >> 6, lane = tid & 63;
  const int wm = wave >> 1, wn = wave & 1;

  const int nbx = gridDim.x;                      // 6
  const int nwg = nbx * gridDim.y;                // 192 per z-plane
  const int orig = blockIdx.y * nbx + blockIdx.x;
  const int cpx = nwg >> 3;
  const int swz = (orig & 7) * cpx + (orig >> 3);
  const int m0 = (swz / nbx) * 128, n0 = (swz % nbx) * 128;
  const int lr = lane & 15, lg = lane >> 4;

  f32x4 acc[4][4];
  #pragma unroll
  for (int i = 0; i < 4; i++)
    #pragma unroll
    for (int j = 0; j < 4; j++) acc[i][j] = f32x4{0.f, 0.f, 0.f, 0.f};

  const u16* Ab[4];
  const u16* Wb[4];
  #pragma unroll
  for (int q = 0; q < 4; ++q) {
    const int u = q * 256 + wave * 64 + lane;
    const int r = u >> 3, c = ((u & 7) ^ (r & 7)) << 3;
    Ab[q] = A + (size_t)(m0 + r) * D_ + c;
    Wb[q] = W + (size_t)(n0 + r) * D_ + c;
  }

#define STAGE128(buf, k0_) do {                                \
    gload16(lA[buf] + wave * 512,        Ab[0] + (k0_));       \
    gload16(lA[buf] + 2048 + wave * 512, Ab[1] + (k0_));       \
    gload16(lA[buf] + 4096 + wave * 512, Ab[2] + (k0_));       \
    gload16(lA[buf] + 6144 + wave * 512, Ab[3] + (k0_));       \
    gload16(lB[buf] + wave * 512,        Wb[0] + (k0_));       \
    gload16(lB[buf] + 2048 + wave * 512, Wb[1] + (k0_));       \
    gload16(lB[buf] + 4096 + wave * 512, Wb[2] + (k0_));       \
    gload16(lB[buf] + 6144 + wave * 512, Wb[3] + (k0_));       \
  } while (0)

  STAGE128(0, 0);
  __syncthreads();

  const int sx = lr & 7;

  int cur = 0;
  for (int kt = 0; kt < 12; ++kt) {
    if (kt < 11) STAGE128(cur ^ 1, (kt + 1) * 64);
    #pragma unroll
    for (int kk = 0; kk < 2; ++kk) {
      const int uo = ((kk * 4 + lg) ^ sx) << 3;
      bf16x8 af[4], bw[4];
      #pragma unroll
      for (int i = 0; i < 4; i++)
        af[i] = ldfrag(lA[cur] + ((wm * 64 + i * 16 + lr) << 6) + uo);
      #pragma unroll
      for (int j = 0; j < 4; j++)
        bw[j] = ldfrag(lB[cur] + ((wn * 64 + j * 16 + lr) << 6) + uo);
      #pragma unroll
      for (int i = 0; i < 4; i++)
        #pragma unroll
        for (int j = 0; j < 4; j++)
          acc[i][j] = mfma16(af[i], bw[j], acc[i][j]);
    }
    __syncthreads();
    cur ^= 1;
  }
#undef STAGE128

  #pragma unroll
  for (int j = 0; j < 4; j++) {
    const int colg = n0 + wn * 64 + j * 16 + lr;
    const float bv = bias[colg];
    #pragma unroll
    for (int i = 0; i < 4; i++) {
      const int rowb = m0 + wm * 64 + i * 16 + lg * 4;
      #pragma unroll
      for (int r = 0; r < 4; r++)
        outb[(size_t)(rowb + r) * D_ + colg] = f2b(acc[i][j][r] + bv);
    }
  }
}

// all-layer Q projection: grid (6, 32, 12)
__global__ __launch_bounds__(256) void qall_kernel(const u16* qsb, const u16* wt60,
                                                   const float* bq, u16* qall) {
  const int l = blockIdx.z;
  gemm128_core(qsb, wt60 + (size_t)l * 5 * DD_, bq + l * D_, qall + (size_t)l * M_ * D_);
}

// per-layer K,V: grid (6, 64, 2)
__global__ __launch_bounds__(256) void kv_kernel(const u16* hidb,
                                                 const u16* wk, const u16* wv,
                                                 const float* bk, const float* bv,
                                                 u16* kout, u16* vtout) {
  if (blockIdx.z == 0) gemm_core(hidb, wk, bk, nullptr, nullptr, kout, nullptr);
  else                 gemm_core(hidb, wv, bv, nullptr, nullptr, nullptr, vtout);
}

// fallback per-layer Q,K,V: grid (6, 64, 3)
__global__ __launch_bounds__(256) void qkv3_kernel(const u16* qsb, const u16* hidb,
                                                   const u16* wq, const u16* wk, const u16* wv,
                                                   const float* bq, const float* bk, const float* bv,
                                                   u16* q, u16* kout, u16* vtout) {
  if (blockIdx.z == 0)      gemm_core(qsb,  wq, bq, nullptr, nullptr, q, nullptr);
  else if (blockIdx.z == 1) gemm_core(hidb, wk, bk, nullptr, nullptr, kout, nullptr);
  else                      gemm_core(hidb, wv, bv, nullptr, nullptr, nullptr, vtout);
}

// o-projection: 64x128 grid (6,64); writes bf16 y (+bf16 residual read)
__global__ __launch_bounds__(256) void o_kernel(const u16* A, const u16* W, const float* bias,
                                                const u16* resb, u16* yb) {
  gemm_core(A, W, bias, resb, nullptr, yb, nullptr);
}

// ---------------- flash attention: block = (b,h, 64 q-rows), 4 waves x 16 rows ----------------
__global__ __launch_bounds__(256) void attn_kernel(const u16* __restrict__ q, const u16* __restrict__ k,
                                                   const u16* __restrict__ vt, const float* __restrict__ mask,
                                                   u16* __restrict__ ctx) {
  __shared__ __align__(16) u16 KT[2][64 * 64];   // [key][dh]
  __shared__ __align__(16) u16 VT[2][64 * 64];   // [dh][key]
  __shared__ __align__(16) u16 PT[4 * 16 * 64];  // per-wave [qrow][key]
  const int tid = threadIdx.x, wave = tid >> 6, lane = tid & 63;
  const int id = blockIdx.x;
  const int bh = id % 96, qblk = id / 96;
  const int b = bh / H_, h = bh % H_;
  const int q0 = qblk * 64 + wave * 16;
  const int lr = lane & 15, lg = lane >> 4;

  bf16x8 qa0, qa1;
  {
    const u16* qp = q + (size_t)(b * T_ + q0 + lr) * D_ + h * DH_ + lg * 8;
    qa0 = ldfrag(qp);
    qa1 = ldfrag(qp + 32);
  }

  const int su0 = wave * 64 + lane, su1 = 256 + wave * 64 + lane;
  const int sr0 = su0 >> 3, sc0 = ((su0 & 7) ^ (sr0 & 7)) << 3;
  const int sr1 = su1 >> 3, sc1 = ((su1 & 7) ^ (sr1 & 7)) << 3;
  const u16* kbase = k + (size_t)b * T_ * D_ + h * DH_;
  const u16* vbase = vt + (size_t)bh * DH_ * T_;

#define STAGEKV(buf, kt_) do {                                                         \
    gload16(KT[buf] + wave * 512,        kbase + (size_t)((kt_) * 64 + sr0) * D_ + sc0); \
    gload16(KT[buf] + 2048 + wave * 512, kbase + (size_t)((kt_) * 64 + sr1) * D_ + sc1); \
    gload16(VT[buf] + wave * 512,        vbase + (size_t)sr0 * T_ + (kt_) * 64 + sc0);   \
    gload16(VT[buf] + 2048 + wave * 512, vbase + (size_t)sr1 * T_ + (kt_) * 64 + sc1);   \
  } while (0)

  float mrow[4] = {-1e30f, -1e30f, -1e30f, -1e30f};
  float lrow[4] = {0.f, 0.f, 0.f, 0.f};
  f32x4 O[4] = { {0,0,0,0}, {0,0,0,0}, {0,0,0,0}, {0,0,0,0} };
  u16* Pw = PT + wave * 1024;

  STAGEKV(0, 0);
  int cur = 0;
  for (int kt = 0; kt < 8; ++kt) {
    __syncthreads();
    if (kt < 7) STAGEKV(cur ^ 1, kt + 1);

    f32x4 S[4];
    __builtin_amdgcn_s_setprio(1);
    #pragma unroll
    for (int nf = 0; nf < 4; ++nf) {
      const u16* kr = KT[cur] + (nf * 16 + lr) * 64;
      bf16x8 kb0 = ldfrag(kr + ((lg       ^ (lr & 7)) << 3));
      bf16x8 kb1 = ldfrag(kr + (((4 + lg) ^ (lr & 7)) << 3));
      f32x4 a = {0.f, 0.f, 0.f, 0.f};
      a = mfma16(qa0, kb0, a);
      a = mfma16(qa1, kb1, a);
      S[nf] = a;
    }
    __builtin_amdgcn_s_setprio(0);
    #pragma unroll
    for (int nf = 0; nf < 4; ++nf) {
      const float mk = mask[(size_t)b * T_ + kt * 64 + nf * 16 + lr];
      #pragma unroll
      for (int r = 0; r < 4; r++) S[nf][r] = S[nf][r] * 0.125f + mk;
    }
    #pragma unroll
    for (int r = 0; r < 4; r++) {
      float tm = fmaxf(fmaxf(S[0][r], S[1][r]), fmaxf(S[2][r], S[3][r]));
      #pragma unroll
      for (int d = 1; d <= 8; d <<= 1) tm = fmaxf(tm, __shfl_xor(tm, d));
      const float mn = fmaxf(mrow[r], tm);
      const float sc = __expf(mrow[r] - mn);
      float ts = 0.f;
      #pragma unroll
      for (int nf = 0; nf < 4; ++nf) { float pv = __expf(S[nf][r] - mn); S[nf][r] = pv; ts += pv; }
      #pragma unroll
      for (int d = 1; d <= 8; d <<= 1) ts += __shfl_xor(ts, d);
      lrow[r] = lrow[r] * sc + ts;
      mrow[r] = mn;
      #pragma unroll
      for (int nf = 0; nf < 4; ++nf) O[nf][r] *= sc;
    }
    #pragma unroll
    for (int nf = 0; nf < 4; ++nf)
      #pragma unroll
      for (int r = 0; r < 4; r++) {
        const int R = lg * 4 + r;
        Pw[R * 64 + ((((nf << 1) | (lr >> 3)) ^ (R & 7)) << 3) + (lr & 7)] = f2b(S[nf][r]);
      }
    __builtin_amdgcn_s_setprio(1);
    #pragma unroll
    for (int ks = 0; ks < 2; ++ks) {
      bf16x8 pa = ldfrag(Pw + lr * 64 + (((ks * 4 + lg) ^ (lr & 7)) << 3));
      #pragma unroll
      for (int nf = 0; nf < 4; ++nf) {
        bf16x8 vb = ldfrag(VT[cur] + (nf * 16 + lr) * 64 + (((ks * 4 + lg) ^ (lr & 7)) << 3));
        O[nf] = mfma16(pa, vb, O[nf]);
      }
    }
    __builtin_amdgcn_s_setprio(0);
    cur ^= 1;
  }
#undef STAGEKV

  #pragma unroll
  for (int r = 0; r < 4; r++) {
    const float inv = 1.f / lrow[r];
    const int row = q0 + lg * 4 + r;
    #pragma unroll
    for (int nf = 0; nf < 4; ++nf)
      ctx[(size_t)(b * T_ + row) * D_ + h * DH_ + nf * 16 + lr] = f2b(O[nf][r] * inv);
  }
}

// ---------------- LayerNorm: one wave per row, bf16 in/out (+f32 final) ----------------
__global__ __launch_bounds__(256) void ln_kernel(const u16* __restrict__ y,
                                                 const float* __restrict__ w, const float* __restrict__ bp,
                                                 float* __restrict__ outf, u16* __restrict__ outb) {
  const int wave = threadIdx.x >> 6, lane = threadIdx.x & 63;
  const int row = blockIdx.x * 4 + wave;
  const u16x4* yp = (const u16x4*)(y + (size_t)row * D_);
  f32x4 x[3];
  #pragma unroll
  for (int j = 0; j < 3; j++) {
    const u16x4 r4 = yp[j * 64 + lane];
    #pragma unroll
    for (int c = 0; c < 4; c++) x[j][c] = b2f(r4[c]);
  }
  float s = 0.f;
  #pragma unroll
  for (int j = 0; j < 3; j++) s += x[j][0] + x[j][1] + x[j][2] + x[j][3];
  #pragma unroll
  for (int d = 1; d <= 32; d <<= 1) s += __shfl_xor(s, d);
  const float u = s * (1.f / D_);
  float v = 0.f;
  #pragma unroll
  for (int j = 0; j < 3; j++)
    #pragma unroll
    for (int c = 0; c < 4; c++) { float t = x[j][c] - u; v += t * t; }
  #pragma unroll
  for (int d = 1; d <= 32; d <<= 1) v += __shfl_xor(v, d);
  const float rinv = rsqrtf(v * (1.f / D_) + 1e-12f);
  const f32x4* wp = (const f32x4*)w;
  const f32x4* bpp = (const f32x4*)bp;
  #pragma unroll
  for (int j = 0; j < 3; j++) {
    const f32x4 w4 = wp[j * 64 + lane];
    const f32x4 b4 = bpp[j * 64 + lane];
    f32x4 o4;
    u16x4 ob;
    #pragma unroll
    for (int c = 0; c < 4; c++) {
      o4[c] = w4[c] * ((x[j][c] - u) * rinv) + b4[c];
      ob[c] = f2b(o4[c]);
    }
    if (outf) ((f32x4*)(outf + (size_t)row * D_))[j * 64 + lane] = o4;
    if (outb) ((u16x4*)(outb + (size_t)row * D_))[j * 64 + lane] = ob;
  }
}

extern "C" void kernel_launch(void* const* d_in, const int* in_sizes, int n_in,
                              void* d_out, int out_size, void* d_ws, size_t ws_size,
                              hipStream_t stream) {
  const float* qs   = (const float*)d_in[0];
  const float* hs   = (const float*)d_in[1];
  const float* mask = (const float*)d_in[2];
  const float* Wq   = (const float*)d_in[3];
  const float* bq   = (const float*)d_in[4];
  const float* Wk   = (const float*)d_in[5];
  const float* bk   = (const float*)d_in[6];
  const float* Wv   = (const float*)d_in[7];
  const float* bv   = (const float*)d_in[8];
  const float* Wo1  = (const float*)d_in[9];
  const float* bo1  = (const float*)d_in[10];
  const float* l1w  = (const float*)d_in[11];
  const float* l1b  = (const float*)d_in[12];
  const float* Wo2  = (const float*)d_in[13];
  const float* bo2  = (const float*)d_in[14];
  const float* l2w  = (const float*)d_in[15];
  const float* l2b  = (const float*)d_in[16];
  float* out = (float*)d_out;

  char* p = (char*)d_ws;
  auto alloc = [&](size_t bytes) { char* r = p; p += (bytes + 255) & ~(size_t)255; return r; };
  u16*   qsb  = (u16*)alloc((size_t)M_ * D_ * 2);
  u16*   hidb = (u16*)alloc((size_t)M_ * D_ * 2);
  u16*   kb_  = (u16*)alloc((size_t)M_ * D_ * 2);
  u16*   vtb  = (u16*)alloc((size_t)M_ * D_ * 2);
  u16*   ctxb = (u16*)alloc((size_t)M_ * D_ * 2);
  u16*   yb   = (u16*)alloc((size_t)M_ * D_ * 2);
  u16*   aob  = (u16*)alloc((size_t)M_ * D_ * 2);
  u16*   qb   = (u16*)alloc((size_t)M_ * D_ * 2);   // fallback per-layer q
  const size_t base_used = (size_t)(p - (char*)d_ws);
  const size_t wt60_bytes = (size_t)60 * DD_ * 2;
  const size_t qall_bytes = (size_t)12 * M_ * D_ * 2;
  const bool wt_once  = (ws_size - base_used) >= wt60_bytes + 512;
  u16* wt60 = (u16*)alloc(wt_once ? wt60_bytes : (size_t)5 * DD_ * 2);
  const size_t used2 = (size_t)(p - (char*)d_ws);
  const bool q_all   = wt_once && (ws_size - used2) >= qall_bytes + 512;
  u16* qall = q_all ? (u16*)alloc(qall_bytes) : qb;

  init_kernel<<<(M_ * D_ + 255) / 256, 256, 0, stream>>>(qs, hs, qsb, hidb, M_ * D_);
  if (wt_once)
    wt_kernel<<<dim3(24, 60), 256, 0, stream>>>(Wq, Wk, Wv, Wo1, Wo2, wt60);
  if (q_all)
    qall_kernel<<<dim3(6, 32, 12), 256, 0, stream>>>(qsb, wt60, bq, qall);

  for (int l = 0; l < L_; ++l) {
    const size_t wo = (size_t)l * DD_;
    u16* wt = wt_once ? (wt60 + (size_t)l * 5 * DD_) : wt60;
    if (!wt_once)
      wt_kernel<<<dim3(24, 5), 256, 0, stream>>>(Wq + wo, Wk + wo, Wv + wo, Wo1 + wo, Wo2 + wo, wt);
    const u16* qcur;
    if (q_all) {
      qcur = qall + (size_t)l * M_ * D_;
      kv_kernel<<<dim3(6, 64, 2), 256, 0, stream>>>(hidb, wt + DD_, wt + 2 * DD_,
                                                    bk + l * D_, bv + l * D_, kb_, vtb);
    } else {
      qcur = qb;
      qkv3_kernel<<<dim3(6, 64, 3), 256, 0, stream>>>(qsb, hidb,
          wt, wt + DD_, wt + 2 * DD_, bq + l * D_, bk + l * D_, bv + l * D_, qb, kb_, vtb);
    }
    attn_kernel<<<768, 256, 0, stream>>>(qcur, kb_, vtb, mask, ctxb);
    o_kernel<<<dim3(6, 64), 256, 0, stream>>>(ctxb, wt + 3 * DD_, bo1 + l * D_, hidb, yb);
    ln_kernel<<<1024, 256, 0, stream>>>(yb, l1w + l * D_, l1b + l * D_, nullptr, aob);
    o_kernel<<<dim3(6, 64), 256, 0, stream>>>(aob, wt + 4 * DD_, bo2 + l * D_, aob, yb);
    ln_kernel<<<1024, 256, 0, stream>>>(yb, l2w + l * D_, l2b + l * D_,
                                        (l == L_ - 1) ? out : nullptr,
                                        (l == L_ - 1) ? nullptr : hidb);
  }
}

// Round 19
// 1112.496 us; speedup vs baseline: 1.0281x; 1.0281x over previous
//
#include <hip/hip_runtime.h>
#include <stdint.h>

#define L_ 12
#define B_ 8
#define T_ 512
#define D_ 768
#define H_ 12
#define DH_ 64
#define M_ 4096               // B_*T_ rows
#define DD_ (D_*D_)

typedef unsigned short u16;
typedef __bf16 bf16x8 __attribute__((ext_vector_type(8)));
typedef float f32x4 __attribute__((ext_vector_type(4)));
typedef u16 u16x4 __attribute__((ext_vector_type(4)));

static __device__ __forceinline__ u16 f2b(float f) {
  union { float f; unsigned u; } x; x.f = f;
  unsigned r = x.u + 0x7fffu + ((x.u >> 16) & 1u);   // RNE
  return (u16)(r >> 16);
}
static __device__ __forceinline__ float b2f(u16 u) {
  union { unsigned u; float f; } x; x.u = ((unsigned)u) << 16; return x.f;
}
static __device__ __forceinline__ void gload16(u16* lds, const u16* g) {
  __builtin_amdgcn_global_load_lds((__attribute__((address_space(1))) void*)(g),
                                   (__attribute__((address_space(3))) void*)(lds), 16, 0, 0);
}
static __device__ __forceinline__ f32x4 mfma16(bf16x8 a, bf16x8 b, f32x4 c) {
  return __builtin_amdgcn_mfma_f32_16x16x32_bf16(a, b, c, 0, 0, 0);
}
static __device__ __forceinline__ bf16x8 ldfrag(const u16* p) {
  return *reinterpret_cast<const bf16x8*>(p);
}

// ---------------- init: f32 -> bf16 copies ----------------
__global__ void init_kernel(const float* __restrict__ qs, const float* __restrict__ hs,
                            u16* __restrict__ qsb, u16* __restrict__ hidb, int n) {
  int i = blockIdx.x * 256 + threadIdx.x;
  if (i < n) {
    qsb[i] = f2b(qs[i]);
    hidb[i] = f2b(hs[i]);
  }
}

// ---------------- weight transpose+convert v3: W[k][n] f32 -> Wt[n][k] bf16 ----------------
__global__ void wt_kernel(const float* W0, const float* W1, const float* W2,
                          const float* W3, const float* W4, u16* __restrict__ out) {
  const int z = blockIdx.y, layer = z / 5, w = z % 5;
  const float* base = (w == 0) ? W0 : (w == 1) ? W1 : (w == 2) ? W2 : (w == 3) ? W3 : W4;
  const float* W = base + (size_t)layer * DD_;
  u16* O = out + (size_t)z * DD_;
  const int nb = blockIdx.x * 32;
  __shared__ u16 tile[32][772];             // stride 1544B: 8B-aligned rows
  const int t = threadIdx.x;
  #pragma unroll
  for (int p = 0; p < 6; ++p) {
    const int g = p * 256 + t;              // 0..1535 : 16-elem groups (4k x 4n)
    const int n4 = (g & 7) * 4, kr4 = (g >> 3) * 4;
    f32x4 v[4];
    #pragma unroll
    for (int j = 0; j < 4; j++)
      v[j] = *reinterpret_cast<const f32x4*>(W + (size_t)(kr4 + j) * D_ + nb + n4);
    #pragma unroll
    for (int i = 0; i < 4; i++) {
      u16x4 w4;
      #pragma unroll
      for (int j = 0; j < 4; j++) w4[j] = f2b(v[j][i]);
      *reinterpret_cast<u16x4*>(&tile[n4 + i][kr4]) = w4;
    }
  }
  __syncthreads();
  #pragma unroll
  for (int p = 0; p < 24; ++p) {
    const int q = p * 256 + t;              // 0..6143 quads
    const int n = q / 192, k4 = (q - n * 192) * 4;
    const u16x4 o4 = *reinterpret_cast<const u16x4*>(&tile[n][k4]);
    *reinterpret_cast<u16x4*>(O + (size_t)(nb + n) * D_ + k4) = o4;
  }
}

// ---------------- GEMM core 64x128, BK=64 (12 phases) ----------------
static __device__ void gemm_core(const u16* __restrict__ A, const u16* __restrict__ W,
                                 const float* __restrict__ bias, const u16* __restrict__ resb,
                                 float* __restrict__ outf, u16* __restrict__ outb,
                                 u16* __restrict__ outv) {
  __shared__ __align__(16) u16 lA[2][64 * 64];
  __shared__ __align__(16) u16 lB[2][128 * 64];
  const int tid = threadIdx.x;
  const int wave = tid >> 6, lane = tid & 63;
  const int wm = wave >> 1, wn = wave & 1;

  const int nbx = gridDim.x;                      // 6
  const int nwg = nbx * gridDim.y;                // 384 per z-plane
  const int orig = blockIdx.y * nbx + blockIdx.x;
  const int cpx = nwg >> 3;
  const int swz = (orig & 7) * cpx + (orig >> 3);
  const int m0 = (swz / nbx) * 64, n0 = (swz % nbx) * 128;
  const int lr = lane & 15, lg = lane >> 4;

  f32x4 acc[2][4];
  #pragma unroll
  for (int i = 0; i < 2; i++)
    #pragma unroll
    for (int j = 0; j < 4; j++) acc[i][j] = f32x4{0.f, 0.f, 0.f, 0.f};

  const int uA0 = wave * 64 + lane, uA1 = 256 + uA0;
  const int rA0 = uA0 >> 3, cA0 = ((uA0 & 7) ^ (rA0 & 7)) << 3;
  const int rA1 = uA1 >> 3, cA1 = ((uA1 & 7) ^ (rA1 & 7)) << 3;
  const u16* Ab0 = A + (size_t)(m0 + rA0) * D_ + cA0;
  const u16* Ab1 = A + (size_t)(m0 + rA1) * D_ + cA1;
  const u16* Wb[4];
  #pragma unroll
  for (int q = 0; q < 4; ++q) {
    const int u = q * 256 + wave * 64 + lane;
    const int r = u >> 3, c = ((u & 7) ^ (r & 7)) << 3;
    Wb[q] = W + (size_t)(n0 + r) * D_ + c;
  }

#define STAGE(buf, k0_) do {                                   \
    gload16(lA[buf] + wave * 512,        Ab0 + (k0_));         \
    gload16(lA[buf] + 2048 + wave * 512, Ab1 + (k0_));         \
    gload16(lB[buf] + wave * 512,        Wb[0] + (k0_));       \
    gload16(lB[buf] + 2048 + wave * 512, Wb[1] + (k0_));       \
    gload16(lB[buf] + 4096 + wave * 512, Wb[2] + (k0_));       \
    gload16(lB[buf] + 6144 + wave * 512, Wb[3] + (k0_));       \
  } while (0)

  STAGE(0, 0);
  __syncthreads();

  const int sx = lr & 7;

  int cur = 0;
  for (int kt = 0; kt < 12; ++kt) {
    if (kt < 11) STAGE(cur ^ 1, (kt + 1) * 64);
    bf16x8 af[2][2], bw[2][4];
    #pragma unroll
    for (int kk = 0; kk < 2; ++kk) {
      const int uo = ((kk * 4 + lg) ^ sx) << 3;
      #pragma unroll
      for (int i = 0; i < 2; i++)
        af[kk][i] = ldfrag(lA[cur] + ((wm * 32 + i * 16 + lr) << 6) + uo);
      #pragma unroll
      for (int j = 0; j < 4; j++)
        bw[kk][j] = ldfrag(lB[cur] + ((wn * 64 + j * 16 + lr) << 6) + uo);
    }
    #pragma unroll
    for (int kk = 0; kk < 2; ++kk)
      #pragma unroll
      for (int i = 0; i < 2; i++)
        #pragma unroll
        for (int j = 0; j < 4; j++)
          acc[i][j] = mfma16(af[kk][i], bw[kk][j], acc[i][j]);
    __syncthreads();
    cur ^= 1;
  }
#undef STAGE

  if (outv) {
    #pragma unroll
    for (int j = 0; j < 4; j++) {
      const int colg = n0 + wn * 64 + j * 16 + lr;
      const float bv = bias[colg];
      const int h = colg >> 6, dh = colg & 63;
      #pragma unroll
      for (int i = 0; i < 2; i++) {
        const int rowb = m0 + wm * 32 + i * 16 + lg * 4;
        const int bb = rowb >> 9, tt = rowb & 511;
        u16x4 o4;
        #pragma unroll
        for (int r = 0; r < 4; r++) o4[r] = f2b(acc[i][j][r] + bv);
        *reinterpret_cast<u16x4*>(outv + ((size_t)((bb * H_ + h) * DH_ + dh)) * T_ + tt) = o4;
      }
    }
    return;
  }
  #pragma unroll
  for (int j = 0; j < 4; j++) {
    const int colg = n0 + wn * 64 + j * 16 + lr;
    const float bv = bias[colg];
    #pragma unroll
    for (int i = 0; i < 2; i++) {
      const int rowb = m0 + wm * 32 + i * 16 + lg * 4;
      #pragma unroll
      for (int r = 0; r < 4; r++) {
        float v = acc[i][j][r] + bv;
        const size_t off = (size_t)(rowb + r) * D_ + colg;
        if (resb) v += b2f(resb[off]);
        if (outf) outf[off] = v;
        if (outb) outb[off] = f2b(v);
      }
    }
  }
}

// ---------------- GEMM core 128x128, BK=64 (qall only) ----------------
static __device__ void gemm128_core(const u16* __restrict__ A, const u16* __restrict__ W,
                                    const float* __restrict__ bias, u16* __restrict__ outb) {
  __shared__ __align__(16) u16 lA[2][128 * 64];
  __shared__ __align__(16) u16 lB[2][128 * 64];
  const int tid = threadIdx.x;
  const int wave = tid >> 6, lane = tid & 63;
  const int wm = wave >> 1, wn = wave & 1;

  const int nbx = gridDim.x;                      // 6
  const int nwg = nbx * gridDim.y;                // 192 per z-plane
  const int orig = blockIdx.y * nbx + blockIdx.x;
  const int cpx = nwg >> 3;
  const int swz = (orig & 7) * cpx + (orig >> 3);
  const int m0 = (swz / nbx) * 128, n0 = (swz % nbx) * 128;
  const int lr = lane & 15, lg = lane >> 4;

  f32x4 acc[4][4];
  #pragma unroll
  for (int i = 0; i < 4; i++)
    #pragma unroll
    for (int j = 0; j < 4; j++) acc[i][j] = f32x4{0.f, 0.f, 0.f, 0.f};

  const u16* Ab[4];
  const u16* Wb[4];
  #pragma unroll
  for (int q = 0; q < 4; ++q) {
    const int u = q * 256 + wave * 64 + lane;
    const int r = u >> 3, c = ((u & 7) ^ (r & 7)) << 3;
    Ab[q] = A + (size_t)(m0 + r) * D_ + c;
    Wb[q] = W + (size_t)(n0 + r) * D_ + c;
  }

#define STAGE128(buf, k0_) do {                                \
    gload16(lA[buf] + wave * 512,        Ab[0] + (k0_));       \
    gload16(lA[buf] + 2048 + wave * 512, Ab[1] + (k0_));       \
    gload16(lA[buf] + 4096 + wave * 512, Ab[2] + (k0_));       \
    gload16(lA[buf] + 6144 + wave * 512, Ab[3] + (k0_));       \
    gload16(lB[buf] + wave * 512,        Wb[0] + (k0_));       \
    gload16(lB[buf] + 2048 + wave * 512, Wb[1] + (k0_));       \
    gload16(lB[buf] + 4096 + wave * 512, Wb[2] + (k0_));       \
    gload16(lB[buf] + 6144 + wave * 512, Wb[3] + (k0_));       \
  } while (0)

  STAGE128(0, 0);
  __syncthreads();

  const int sx = lr & 7;

  int cur = 0;
  for (int kt = 0; kt < 12; ++kt) {
    if (kt < 11) STAGE128(cur ^ 1, (kt + 1) * 64);
    #pragma unroll
    for (int kk = 0; kk < 2; ++kk) {
      const int uo = ((kk * 4 + lg) ^ sx) << 3;
      bf16x8 af[4], bw[4];
      #pragma unroll
      for (int i = 0; i < 4; i++)
        af[i] = ldfrag(lA[cur] + ((wm * 64 + i * 16 + lr) << 6) + uo);
      #pragma unroll
      for (int j = 0; j < 4; j++)
        bw[j] = ldfrag(lB[cur] + ((wn * 64 + j * 16 + lr) << 6) + uo);
      #pragma unroll
      for (int i = 0; i < 4; i++)
        #pragma unroll
        for (int j = 0; j < 4; j++)
          acc[i][j] = mfma16(af[i], bw[j], acc[i][j]);
    }
    __syncthreads();
    cur ^= 1;
  }
#undef STAGE128

  #pragma unroll
  for (int j = 0; j < 4; j++) {
    const int colg = n0 + wn * 64 + j * 16 + lr;
    const float bv = bias[colg];
    #pragma unroll
    for (int i = 0; i < 4; i++) {
      const int rowb = m0 + wm * 64 + i * 16 + lg * 4;
      #pragma unroll
      for (int r = 0; r < 4; r++)
        outb[(size_t)(rowb + r) * D_ + colg] = f2b(acc[i][j][r] + bv);
    }
  }
}

// all-layer Q projection: grid (6, 32, 12)
__global__ __launch_bounds__(256) void qall_kernel(const u16* qsb, const u16* wt60,
                                                   const float* bq, u16* qall) {
  const int l = blockIdx.z;
  gemm128_core(qsb, wt60 + (size_t)l * 5 * DD_, bq + l * D_, qall + (size_t)l * M_ * D_);
}

// per-layer K,V: grid (6, 64, 2)
__global__ __launch_bounds__(256) void kv_kernel(const u16* hidb,
                                                 const u16* wk, const u16* wv,
                                                 const float* bk, const float* bv,
                                                 u16* kout, u16* vtout) {
  if (blockIdx.z == 0) gemm_core(hidb, wk, bk, nullptr, nullptr, kout, nullptr);
  else                 gemm_core(hidb, wv, bv, nullptr, nullptr, nullptr, vtout);
}

// fallback per-layer Q,K,V: grid (6, 64, 3)
__global__ __launch_bounds__(256) void qkv3_kernel(const u16* qsb, const u16* hidb,
                                                   const u16* wq, const u16* wk, const u16* wv,
                                                   const float* bq, const float* bk, const float* bv,
                                                   u16* q, u16* kout, u16* vtout) {
  if (blockIdx.z == 0)      gemm_core(qsb,  wq, bq, nullptr, nullptr, q, nullptr);
  else if (blockIdx.z == 1) gemm_core(hidb, wk, bk, nullptr, nullptr, kout, nullptr);
  else                      gemm_core(hidb, wv, bv, nullptr, nullptr, nullptr, vtout);
}

// o-projection: 64x128 grid (6,64); writes bf16 y (+bf16 residual read)
__global__ __launch_bounds__(256) void o_kernel(const u16* A, const u16* W, const float* bias,
                                                const u16* resb, u16* yb) {
  gemm_core(A, W, bias, resb, nullptr, yb, nullptr);
}

// ---------------- flash attention: block = (b,h, 64 q-rows), 4 waves x 16 rows ----------------
__global__ __launch_bounds__(256) void attn_kernel(const u16* __restrict__ q, const u16* __restrict__ k,
                                                   const u16* __restrict__ vt, const float* __restrict__ mask,
                                                   u16* __restrict__ ctx) {
  __shared__ __align__(16) u16 KT[2][64 * 64];   // [key][dh]
  __shared__ __align__(16) u16 VT[2][64 * 64];   // [dh][key]
  __shared__ __align__(16) u16 PT[4 * 16 * 64];  // per-wave [qrow][key]
  const int tid = threadIdx.x, wave = tid >> 6, lane = tid & 63;
  const int id = blockIdx.x;
  const int bh = id % 96, qblk = id / 96;
  const int b = bh / H_, h = bh % H_;
  const int q0 = qblk * 64 + wave * 16;
  const int lr = lane & 15, lg = lane >> 4;

  bf16x8 qa0, qa1;
  {
    const u16* qp = q + (size_t)(b * T_ + q0 + lr) * D_ + h * DH_ + lg * 8;
    qa0 = ldfrag(qp);
    qa1 = ldfrag(qp + 32);
  }

  const int su0 = wave * 64 + lane, su1 = 256 + wave * 64 + lane;
  const int sr0 = su0 >> 3, sc0 = ((su0 & 7) ^ (sr0 & 7)) << 3;
  const int sr1 = su1 >> 3, sc1 = ((su1 & 7) ^ (sr1 & 7)) << 3;
  const u16* kbase = k + (size_t)b * T_ * D_ + h * DH_;
  const u16* vbase = vt + (size_t)bh * DH_ * T_;

#define STAGEKV(buf, kt_) do {                                                         \
    gload16(KT[buf] + wave * 512,        kbase + (size_t)((kt_) * 64 + sr0) * D_ + sc0); \
    gload16(KT[buf] + 2048 + wave * 512, kbase + (size_t)((kt_) * 64 + sr1) * D_ + sc1); \
    gload16(VT[buf] + wave * 512,        vbase + (size_t)sr0 * T_ + (kt_) * 64 + sc0);   \
    gload16(VT[buf] + 2048 + wave * 512, vbase + (size_t)sr1 * T_ + (kt_) * 64 + sc1);   \
  } while (0)

  float mrow[4] = {-1e30f, -1e30f, -1e30f, -1e30f};
  float lrow[4] = {0.f, 0.f, 0.f, 0.f};
  f32x4 O[4] = { {0,0,0,0}, {0,0,0,0}, {0,0,0,0}, {0,0,0,0} };
  u16* Pw = PT + wave * 1024;

  STAGEKV(0, 0);
  int cur = 0;
  for (int kt = 0; kt < 8; ++kt) {
    __syncthreads();
    if (kt < 7) STAGEKV(cur ^ 1, kt + 1);

    f32x4 S[4];
    __builtin_amdgcn_s_setprio(1);
    #pragma unroll
    for (int nf = 0; nf < 4; ++nf) {
      const u16* kr = KT[cur] + (nf * 16 + lr) * 64;
      bf16x8 kb0 = ldfrag(kr + ((lg       ^ (lr & 7)) << 3));
      bf16x8 kb1 = ldfrag(kr + (((4 + lg) ^ (lr & 7)) << 3));
      f32x4 a = {0.f, 0.f, 0.f, 0.f};
      a = mfma16(qa0, kb0, a);
      a = mfma16(qa1, kb1, a);
      S[nf] = a;
    }
    __builtin_amdgcn_s_setprio(0);
    #pragma unroll
    for (int nf = 0; nf < 4; ++nf) {
      const float mk = mask[(size_t)b * T_ + kt * 64 + nf * 16 + lr];
      #pragma unroll
      for (int r = 0; r < 4; r++) S[nf][r] = S[nf][r] * 0.125f + mk;
    }
    #pragma unroll
    for (int r = 0; r < 4; r++) {
      float tm = fmaxf(fmaxf(S[0][r], S[1][r]), fmaxf(S[2][r], S[3][r]));
      #pragma unroll
      for (int d = 1; d <= 8; d <<= 1) tm = fmaxf(tm, __shfl_xor(tm, d));
      const float mn = fmaxf(mrow[r], tm);
      const float sc = __expf(mrow[r] - mn);
      float ts = 0.f;
      #pragma unroll
      for (int nf = 0; nf < 4; ++nf) { float pv = __expf(S[nf][r] - mn); S[nf][r] = pv; ts += pv; }
      #pragma unroll
      for (int d = 1; d <= 8; d <<= 1) ts += __shfl_xor(ts, d);
      lrow[r] = lrow[r] * sc + ts;
      mrow[r] = mn;
      #pragma unroll
      for (int nf = 0; nf < 4; ++nf) O[nf][r] *= sc;
    }
    #pragma unroll
    for (int nf = 0; nf < 4; ++nf)
      #pragma unroll
      for (int r = 0; r < 4; r++) {
        const int R = lg * 4 + r;
        Pw[R * 64 + ((((nf << 1) | (lr >> 3)) ^ (R & 7)) << 3) + (lr & 7)] = f2b(S[nf][r]);
      }
    __builtin_amdgcn_s_setprio(1);
    #pragma unroll
    for (int ks = 0; ks < 2; ++ks) {
      bf16x8 pa = ldfrag(Pw + lr * 64 + (((ks * 4 + lg) ^ (lr & 7)) << 3));
      #pragma unroll
      for (int nf = 0; nf < 4; ++nf) {
        bf16x8 vb = ldfrag(VT[cur] + (nf * 16 + lr) * 64 + (((ks * 4 + lg) ^ (lr & 7)) << 3));
        O[nf] = mfma16(pa, vb, O[nf]);
      }
    }
    __builtin_amdgcn_s_setprio(0);
    cur ^= 1;
  }
#undef STAGEKV

  #pragma unroll
  for (int r = 0; r < 4; r++) {
    const float inv = 1.f / lrow[r];
    const int row = q0 + lg * 4 + r;
    #pragma unroll
    for (int nf = 0; nf < 4; ++nf)
      ctx[(size_t)(b * T_ + row) * D_ + h * DH_ + nf * 16 + lr] = f2b(O[nf][r] * inv);
  }
}

// ---------------- LayerNorm: one wave per row, bf16 in/out (+f32 final) ----------------
__global__ __launch_bounds__(256) void ln_kernel(const u16* __restrict__ y,
                                                 const float* __restrict__ w, const float* __restrict__ bp,
                                                 float* __restrict__ outf, u16* __restrict__ outb) {
  const int wave = threadIdx.x >> 6, lane = threadIdx.x & 63;
  const int row = blockIdx.x * 4 + wave;
  const u16x4* yp = (const u16x4*)(y + (size_t)row * D_);
  f32x4 x[3];
  #pragma unroll
  for (int j = 0; j < 3; j++) {
    const u16x4 r4 = yp[j * 64 + lane];
    #pragma unroll
    for (int c = 0; c < 4; c++) x[j][c] = b2f(r4[c]);
  }
  float s = 0.f;
  #pragma unroll
  for (int j = 0; j < 3; j++) s += x[j][0] + x[j][1] + x[j][2] + x[j][3];
  #pragma unroll
  for (int d = 1; d <= 32; d <<= 1) s += __shfl_xor(s, d);
  const float u = s * (1.f / D_);
  float v = 0.f;
  #pragma unroll
  for (int j = 0; j < 3; j++)
    #pragma unroll
    for (int c = 0; c < 4; c++) { float t = x[j][c] - u; v += t * t; }
  #pragma unroll
  for (int d = 1; d <= 32; d <<= 1) v += __shfl_xor(v, d);
  const float rinv = rsqrtf(v * (1.f / D_) + 1e-12f);
  const f32x4* wp = (const f32x4*)w;
  const f32x4* bpp = (const f32x4*)bp;
  #pragma unroll
  for (int j = 0; j < 3; j++) {
    const f32x4 w4 = wp[j * 64 + lane];
    const f32x4 b4 = bpp[j * 64 + lane];
    f32x4 o4;
    u16x4 ob;
    #pragma unroll
    for (int c = 0; c < 4; c++) {
      o4[c] = w4[c] * ((x[j][c] - u) * rinv) + b4[c];
      ob[c] = f2b(o4[c]);
    }
    if (outf) ((f32x4*)(outf + (size_t)row * D_))[j * 64 + lane] = o4;
    if (outb) ((u16x4*)(outb + (size_t)row * D_))[j * 64 + lane] = ob;
  }
}

extern "C" void kernel_launch(void* const* d_in, const int* in_sizes, int n_in,
                              void* d_out, int out_size, void* d_ws, size_t ws_size,
                              hipStream_t stream) {
  const float* qs   = (const float*)d_in[0];
  const float* hs   = (const float*)d_in[1];
  const float* mask = (const float*)d_in[2];
  const float* Wq   = (const float*)d_in[3];
  const float* bq   = (const float*)d_in[4];
  const float* Wk   = (const float*)d_in[5];
  const float* bk   = (const float*)d_in[6];
  const float* Wv   = (const float*)d_in[7];
  const float* bv   = (const float*)d_in[8];
  const float* Wo1  = (const float*)d_in[9];
  const float* bo1  = (const float*)d_in[10];
  const float* l1w  = (const float*)d_in[11];
  const float* l1b  = (const float*)d_in[12];
  const float* Wo2  = (const float*)d_in[13];
  const float* bo2  = (const float*)d_in[14];
  const float* l2w  = (const float*)d_in[15];
  const float* l2b  = (const float*)d_in[16];
  float* out = (float*)d_out;

  char* p = (char*)d_ws;
  auto alloc = [&](size_t bytes) { char* r = p; p += (bytes + 255) & ~(size_t)255; return r; };
  u16*   qsb  = (u16*)alloc((size_t)M_ * D_ * 2);
  u16*   hidb = (u16*)alloc((size_t)M_ * D_ * 2);
  u16*   kb_  = (u16*)alloc((size_t)M_ * D_ * 2);
  u16*   vtb  = (u16*)alloc((size_t)M_ * D_ * 2);
  u16*   ctxb = (u16*)alloc((size_t)M_ * D_ * 2);
  u16*   yb   = (u16*)alloc((size_t)M_ * D_ * 2);
  u16*   aob  = (u16*)alloc((size_t)M_ * D_ * 2);
  u16*   qb   = (u16*)alloc((size_t)M_ * D_ * 2);   // fallback per-layer q
  const size_t base_used = (size_t)(p - (char*)d_ws);
  const size_t wt60_bytes = (size_t)60 * DD_ * 2;
  const size_t qall_bytes = (size_t)12 * M_ * D_ * 2;
  const bool wt_once  = (ws_size - base_used) >= wt60_bytes + 512;
  u16* wt60 = (u16*)alloc(wt_once ? wt60_bytes : (size_t)5 * DD_ * 2);
  const size_t used2 = (size_t)(p - (char*)d_ws);
  const bool q_all   = wt_once && (ws_size - used2) >= qall_bytes + 512;
  u16* qall = q_all ? (u16*)alloc(qall_bytes) : qb;

  init_kernel<<<(M_ * D_ + 255) / 256, 256, 0, stream>>>(qs, hs, qsb, hidb, M_ * D_);
  if (wt_once)
    wt_kernel<<<dim3(24, 60), 256, 0, stream>>>(Wq, Wk, Wv, Wo1, Wo2, wt60);
  if (q_all)
    qall_kernel<<<dim3(6, 32, 12), 256, 0, stream>>>(qsb, wt60, bq, qall);

  for (int l = 0; l < L_; ++l) {
    const size_t wo = (size_t)l * DD_;
    u16* wt = wt_once ? (wt60 + (size_t)l * 5 * DD_) : wt60;
    if (!wt_once)
      wt_kernel<<<dim3(24, 5), 256, 0, stream>>>(Wq + wo, Wk + wo, Wv + wo, Wo1 + wo, Wo2 + wo, wt);
    const u16* qcur;
    if (q_all) {
      qcur = qall + (size_t)l * M_ * D_;
      kv_kernel<<<dim3(6, 64, 2), 256, 0, stream>>>(hidb, wt + DD_, wt + 2 * DD_,
                                                    bk + l * D_, bv + l * D_, kb_, vtb);
    } else {
      qcur = qb;
      qkv3_kernel<<<dim3(6, 64, 3), 256, 0, stream>>>(qsb, hidb,
          wt, wt + DD_, wt + 2 * DD_, bq + l * D_, bk + l * D_, bv + l * D_, qb, kb_, vtb);
    }
    attn_kernel<<<768, 256, 0, stream>>>(qcur, kb_, vtb, mask, ctxb);
    o_kernel<<<dim3(6, 64), 256, 0, stream>>>(ctxb, wt + 3 * DD_, bo1 + l * D_, hidb, yb);
    ln_kernel<<<1024, 256, 0, stream>>>(yb, l1w + l * D_, l1b + l * D_, nullptr, aob);
    o_kernel<<<dim3(6, 64), 256, 0, stream>>>(aob, wt + 4 * DD_, bo2 + l * D_, aob, yb);
    ln_kernel<<<1024, 256, 0, stream>>>(yb, l2w + l * D_, l2b + l * D_,
                                        (l == L_ - 1) ? out : nullptr,
                                        (l == L_ - 1) ? nullptr : hidb);
  }
}